// Round 13
// baseline (227.113 us; speedup 1.0000x reference)
//
#include <hip/hip_runtime.h>
#include <math.h>

// Problem constants: B=1, C=16, H=72, W=96, N=6912
#define NPIX 6912
#define IMW  96
#define JCH  128               // j per chunk (8 tiles of 16)
#define GJ   54                // chunk count: 54*128 = 6912
#define NTILE 8

// d_ws float-offset layout (44*N floats = 1.22 MB)
#define OFF_PACK1 0                         // [N][4] f32: x0,x1,x2,sq1
#define OFF_PACK2 (NPIX * 4)                // [N][8] f32 scaled: -2ct2*y, ct2*sq2 | noisy
#define OFF_F1P   (NPIX * 12)               // [N][32] f16: h1[16] | l1[16]  (64B/row)
#define OFF_F2P   (NPIX * 28)               // [N][32] f16: h2[16] | l2[16]

#if __has_builtin(__builtin_amdgcn_exp2f)
#define EXP2F(x) __builtin_amdgcn_exp2f(x)
#else
#define EXP2F(x) exp2f(x)
#endif
#if __has_builtin(__builtin_amdgcn_sqrtf)
#define SQRTF(x) __builtin_amdgcn_sqrtf(x)
#else
#define SQRTF(x) sqrtf(x)
#endif
#define NEG_COEF_LOG2E (-0.14426950408889634f)   // -0.1 * log2(e)
#define CT2   (NEG_COEF_LOG2E * NEG_COEF_LOG2E)  // (0.1*log2e)^2
#define M2CT2 (-2.0f * CT2)

typedef _Float16 f16x8 __attribute__((ext_vector_type(8)));
typedef float f32x4v __attribute__((ext_vector_type(4)));

// pack two f16 into one float's bit pattern (lo half = a, hi half = b)
__device__ __forceinline__ float packh2(_Float16 a, _Float16 b) {
  unsigned short ua = __builtin_bit_cast(unsigned short, a);
  unsigned short ub = __builtin_bit_cast(unsigned short, b);
  unsigned int u = (unsigned int)ua | ((unsigned int)ub << 16);
  return __builtin_bit_cast(float, u);
}

__device__ __forceinline__ float blk_reduce256(float v) {
  __shared__ float sm[4];
#pragma unroll
  for (int o = 32; o > 0; o >>= 1) v += __shfl_down(v, o, 64);
  const int lane = threadIdx.x & 63;
  const int wv = threadIdx.x >> 6;
  if (lane == 0) sm[wv] = v;
  __syncthreads();
  return (sm[0] + sm[1]) + (sm[2] + sm[3]);
}

// Per-pixel precompute: PACK1 (raw), PACK2 (pre-scaled by -2*ct2 / ct2 so the
// main-loop distance is 4 FMA-class ops + exp2(-sqrt(s)) with folded neg),
// and hi/lo-f16 normalized features for the MFMA gram (f = h + l).
__global__ __launch_bounds__(256) void k_pre(
    const float* __restrict__ f1, const float* __restrict__ f2,
    const float* __restrict__ dep1, const float* __restrict__ dep2,
    const float* __restrict__ pose, const float* __restrict__ noise,
    float* __restrict__ ws, float* __restrict__ out) {
  __shared__ float sPose[24];
  const int t = threadIdx.x;
  if (t < 12) {
    sPose[t] = pose[t];
  } else if (t < 24) {
    const int u = t - 12, r = u >> 2, c = u & 3;
    float s = 0.f;
#pragma unroll
    for (int k = 0; k < 4; ++k) s = fmaf(pose[r * 4 + k], noise[k * 4 + c], s);
    sPose[t] = s;
  }
  __syncthreads();

  const int i = blockIdx.x * 256 + t;
  const int vi = i / IMW;
  const int ui = i - vi * IMW;
  const float inv48 = (float)(1.0 / 48.0);
  const float p1c = fmaf((float)ui, inv48, -1.0f);
  const float p2c = fmaf((float)vi, inv48, -0.75f);

  const float d1 = dep1[i];
  const float x0 = d1, x1 = d1 * p1c, x2 = d1 * p2c;
  const float sq1 = fmaf(x2, x2, fmaf(x1, x1, x0 * x0));
  *(float4*)(ws + OFF_PACK1 + (size_t)i * 4) = make_float4(x0, x1, x2, sq1);

  const float d2 = dep2[i];
  const float w0 = d2, w1 = d2 * p1c, w2 = d2 * p2c;
  const float* P  = sPose;
  const float* Pn = sPose + 12;
  const float y0 = fmaf(P[0], w0, fmaf(P[1], w1, fmaf(P[2],  w2, P[3])));
  const float y1 = fmaf(P[4], w0, fmaf(P[5], w1, fmaf(P[6],  w2, P[7])));
  const float y2 = fmaf(P[8], w0, fmaf(P[9], w1, fmaf(P[10], w2, P[11])));
  const float sq2 = fmaf(y2, y2, fmaf(y1, y1, y0 * y0));
  const float z0 = fmaf(Pn[0], w0, fmaf(Pn[1], w1, fmaf(Pn[2],  w2, Pn[3])));
  const float z1 = fmaf(Pn[4], w0, fmaf(Pn[5], w1, fmaf(Pn[6],  w2, Pn[7])));
  const float z2 = fmaf(Pn[8], w0, fmaf(Pn[9], w1, fmaf(Pn[10], w2, Pn[11])));
  const float sq2n = fmaf(z2, z2, fmaf(z1, z1, z0 * z0));
  // pre-scaled: s = ct2*d2 accumulates as (ct2*sq1) + (ct2*sq2) + x.(-2ct2*y)
  *(float4*)(ws + OFF_PACK2 + (size_t)i * 8) =
      make_float4(M2CT2 * y0, M2CT2 * y1, M2CT2 * y2, CT2 * sq2);
  *(float4*)(ws + OFF_PACK2 + (size_t)i * 8 + 4) =
      make_float4(M2CT2 * z0, M2CT2 * z1, M2CT2 * z2, CT2 * sq2n);

  float a[16], b[16];
  float sa = 0.f, sb = 0.f;
#pragma unroll
  for (int c = 0; c < 16; ++c) {
    a[c] = f1[c * NPIX + i]; sa = fmaf(a[c], a[c], sa);
    b[c] = f2[c * NPIX + i]; sb = fmaf(b[c], b[c], sb);
  }
  const float na = sqrtf(sa), nb = sqrtf(sb);
#pragma unroll
  for (int c = 0; c < 16; ++c) { a[c] = a[c] / na; b[c] = b[c] / nb; }

  // hi/lo f16 split: row = [h(32B) | l(32B)]
  _Float16 h1v[16], l1v[16], h2v[16], l2v[16];
#pragma unroll
  for (int c = 0; c < 16; ++c) {
    _Float16 h = (_Float16)a[c];
    h1v[c] = h; l1v[c] = (_Float16)(a[c] - (float)h);
    _Float16 g = (_Float16)b[c];
    h2v[c] = g; l2v[c] = (_Float16)(b[c] - (float)g);
  }
  float4* p1 = (float4*)(ws + OFF_F1P) + (size_t)i * 4;
  float4* p2 = (float4*)(ws + OFF_F2P) + (size_t)i * 4;
#pragma unroll
  for (int k = 0; k < 2; ++k) {
    p1[k]     = make_float4(packh2(h1v[k*8+0],h1v[k*8+1]), packh2(h1v[k*8+2],h1v[k*8+3]),
                            packh2(h1v[k*8+4],h1v[k*8+5]), packh2(h1v[k*8+6],h1v[k*8+7]));
    p1[k + 2] = make_float4(packh2(l1v[k*8+0],l1v[k*8+1]), packh2(l1v[k*8+2],l1v[k*8+3]),
                            packh2(l1v[k*8+4],l1v[k*8+5]), packh2(l1v[k*8+6],l1v[k*8+7]));
    p2[k]     = make_float4(packh2(h2v[k*8+0],h2v[k*8+1]), packh2(h2v[k*8+2],h2v[k*8+3]),
                            packh2(h2v[k*8+4],h2v[k*8+5]), packh2(h2v[k*8+6],h2v[k*8+7]));
    p2[k + 2] = make_float4(packh2(l2v[k*8+0],l2v[k*8+1]), packh2(l2v[k*8+2],l2v[k*8+3]),
                            packh2(l2v[k*8+4],l2v[k*8+5]), packh2(l2v[k*8+6],l2v[k*8+7]));
  }
  const float part = blk_reduce256(na + nb);
  if (t == 0) atomicAdd(out + 2, 100.0f * part);
}

// Main reduction. Wave owns a 16-row i-tile; per 16x16 j-tile the gram comes
// from 2 x mfma_f32_16x16x32_f16 (A=[h1|l1], B1=[h2|h2], B2=[l2|0]).
// LDS is staged in FRAGMENT ORDER so every main-loop ds_read is linear-per-
// lane (conflict-free) or a same-address broadcast:
//   sB1[tile][lane]   : b1 fragment (16B)  -- 8KB
//   sB2[tile][l<32]   : b2 fragment (l2)   -- 4KB (g>=2 reads broadcast zero)
//   sD[tile*16+c]     : q|r, rows padded to 48B (word stride 12 -> 2-way free)
__global__ __launch_bounds__(256) void k_main(const float* __restrict__ ws,
                                              float* __restrict__ out) {
  __shared__ float4 sB1[NTILE * 64];
  __shared__ float4 sB2[NTILE * 32];
  __shared__ float4 sD[NTILE * 16 * 3];
  __shared__ float4 sZ[1];

  const int t = threadIdx.x;
  const int j0 = blockIdx.y * JCH;
  const float4* gF = (const float4*)(ws + OFF_F2P)   + (size_t)j0 * 4;  // [row][4]
  const float4* gD = (const float4*)(ws + OFF_PACK2) + (size_t)j0 * 2;  // [row][2]

  // stage B1 fragments: entry (tile, l) = h2 quad ((l>>4)&1) of row tile*16+(l&15)
  for (int idx = t; idx < NTILE * 64; idx += 256) {
    const int tile = idx >> 6, l = idx & 63;
    sB1[idx] = gF[(tile * 16 + (l & 15)) * 4 + ((l >> 4) & 1)];
  }
  // stage B2 fragments (lanes 0..31 only): l2 quad (l>>4) of row tile*16+(l&15)
  for (int idx = t; idx < NTILE * 32; idx += 256) {
    const int tile = idx >> 5, l = idx & 31;
    sB2[idx] = gF[(tile * 16 + (l & 15)) * 4 + 2 + (l >> 4)];
  }
  // stage D (row stride 3 float4: q, r, pad)
  for (int idx = t; idx < NTILE * 16 * 2; idx += 256) {
    const int row = idx >> 1, half = idx & 1;
    sD[row * 3 + half] = gD[row * 2 + half];
  }
  if (t == 0) sZ[0] = make_float4(0.f, 0.f, 0.f, 0.f);

  const int wid = t >> 6, lane = t & 63;
  const int c = lane & 15, g = lane >> 4;
  const int rowbase = (blockIdx.x * 4 + wid) * 16;

  // A-frag (per-kernel constant): lane -> row rowbase+c, k-octet g
  const f16x8 afrag = *(const f16x8*)((const char*)(ws + OFF_F1P)
                                      + (size_t)(rowbase + c) * 64 + g * 16);
  // x/sq1 for this lane's 4 output rows (rows g*4+p); pre-scale sq1 by ct2
  float4 xr[4];
#pragma unroll
  for (int p = 0; p < 4; ++p) {
    xr[p] = *(const float4*)(ws + OFF_PACK1 + (size_t)(rowbase + g * 4 + p) * 4);
    xr[p].w *= CT2;
  }

  __syncthreads();

  const float4* pb2 = (lane < 32) ? (sB2 + lane) : sZ;
  const int st2 = (lane < 32) ? 32 : 0;

  float accv = 0.f;
  for (int jt = 0; jt < NTILE; ++jt) {
    const f16x8 b1 = *(const f16x8*)(sB1 + jt * 64 + lane);
    const f16x8 b2 = *(const f16x8*)(pb2 + jt * st2);
    f32x4v acc = {0.f, 0.f, 0.f, 0.f};
    acc = __builtin_amdgcn_mfma_f32_16x16x32_f16(afrag, b1, acc, 0, 0, 0);
    acc = __builtin_amdgcn_mfma_f32_16x16x32_f16(afrag, b2, acc, 0, 0, 0);

    const float4 q = sD[(jt * 16 + c) * 3];
    const float4 r = sD[(jt * 16 + c) * 3 + 1];
#pragma unroll
    for (int p = 0; p < 4; ++p) {
      const float4 X = xr[p];
      float s1 = X.w + q.w;
      s1 = fmaf(X.x, q.x, s1);
      s1 = fmaf(X.y, q.y, s1);
      s1 = fmaf(X.z, q.z, s1);
      s1 = fmaxf(s1, 0.f);
      const float k1 = EXP2F(-SQRTF(s1));
      float s2 = X.w + r.w;
      s2 = fmaf(X.x, r.x, s2);
      s2 = fmaf(X.y, r.y, s2);
      s2 = fmaf(X.z, r.z, s2);
      s2 = fmaxf(s2, 0.f);
      const float k2 = EXP2F(-SQRTF(s2));
      accv = fmaf(k1 - k2, acc[p], accv);
    }
  }
  const float part = blk_reduce256(accv);
  if (t == 0) {
    atomicAdd(out + 0, -part);   // final_loss
    atomicAdd(out + 1, -part);   // inner_neg
  }
}

extern "C" void kernel_launch(void* const* d_in, const int* in_sizes, int n_in,
                              void* d_out, int out_size, void* d_ws, size_t ws_size,
                              hipStream_t stream) {
  const float* f1    = (const float*)d_in[0];
  const float* f2    = (const float*)d_in[1];
  const float* dep1  = (const float*)d_in[2];
  const float* dep2  = (const float*)d_in[3];
  const float* pose  = (const float*)d_in[4];
  const float* noise = (const float*)d_in[5];
  float* out = (float*)d_out;
  float* ws  = (float*)d_ws;

  (void)hipMemsetAsync(out, 0, (size_t)out_size * sizeof(float), stream);
  k_pre<<<NPIX / 256, 256, 0, stream>>>(f1, f2, dep1, dep2, pose, noise, ws, out);
  k_main<<<dim3(NPIX / (4 * 16), GJ), 256, 0, stream>>>(ws, out);
}